// Round 9
// baseline (817.596 us; speedup 1.0000x reference)
//
#include <hip/hip_runtime.h>
#include <hip/hip_bf16.h>
#include <math.h>

#define DIM   384
#define HEADS 8
#define HD    48
#define NTOK  32768   // 8 * 64 * 64
#define NWIN  512     // 8 images * 64 windows

typedef __attribute__((ext_vector_type(8))) short bf16x8;
typedef __attribute__((ext_vector_type(8))) unsigned short u16x8;
typedef __attribute__((ext_vector_type(4))) float f32x4;

__device__ __forceinline__ float bf2f(unsigned short u) {
    unsigned int v = ((unsigned int)u) << 16;
    return __uint_as_float(v);
}
// RNE f32->bf16 via native cast (proven bit-identical in R5-R8 bench)
__device__ __forceinline__ unsigned short f2bf(float f) {
    __bf16 b = (__bf16)f;
    return __builtin_bit_cast(unsigned short, b);
}

// branchless erf-based GELU (A&S 7.1.25 3-term, |err_erf| < 2.5e-5 << bf16 ulp)
__device__ __forceinline__ float gelu(float v) {
    float z  = v * 0.70710678118654752f;
    float az = fabsf(z);
    float t  = __builtin_amdgcn_rcpf(1.0f + 0.47047f * az);
    float p  = t * (0.3480242f + t * (-0.0958798f + t * 0.7478556f));
    float ea = 1.0f - p * __expf(-az * az);
    float er = copysignf(ea, z);
    return 0.5f * v * (1.0f + er);
}

// token (window order) -> source pixel of x (accounting for roll by -SHIFT)
__device__ __forceinline__ void tok2src(int tok, int& b, int& hs, int& ws) {
    int bb  = tok >> 12;
    int win = (tok >> 6) & 63;
    int t   = tok & 63;
    int hi = win >> 3, wi = win & 7;
    int r  = t >> 3,  cc = t & 7;
    b  = bb;
    hs = (hi * 8 + r  + 4) & 63;
    ws = (wi * 8 + cc + 4) & 63;
}

// ------------- weight convert f32 [K][N] -> bf16 [N][K], coalesced both
// sides via 64x64 LDS tile transpose. One block = one 64x64 tile.
__global__ __launch_bounds__(256) void k_wt4(const float* __restrict__ qkv_w,
                                             const float* __restrict__ proj_w,
                                             const float* __restrict__ w1,
                                             const float* __restrict__ w2,
                                             unsigned short* __restrict__ d0,
                                             unsigned short* __restrict__ d1,
                                             unsigned short* __restrict__ d2,
                                             unsigned short* __restrict__ d3) {
    // tiles: qkv 6x18=108 | proj 6x6=36 | w1 6x24=144 | w2 24x6=144  => 432
    __shared__ unsigned short T[64][66];
    int b = blockIdx.x;
    const float* W; unsigned short* Wt; int K, N, lt;
    if (b < 108)      { W = qkv_w;  Wt = d0; K = 384;  N = 1152; lt = b; }
    else if (b < 144) { W = proj_w; Wt = d1; K = 384;  N = 384;  lt = b - 108; }
    else if (b < 288) { W = w1;     Wt = d2; K = 384;  N = 1536; lt = b - 144; }
    else              { W = w2;     Wt = d3; K = 1536; N = 384;  lt = b - 288; }
    int tn = N >> 6;
    int k0 = (lt / tn) << 6, n0 = (lt % tn) << 6;
    int t  = threadIdx.x;
    int cl = t & 63, rw = t >> 6;
    #pragma unroll
    for (int p = 0; p < 16; p++) {
        int kk = p * 4 + rw;
        T[cl][kk] = f2bf(W[(size_t)(k0 + kk) * N + n0 + cl]);  // coalesced in n
    }
    __syncthreads();
    #pragma unroll
    for (int p = 0; p < 16; p++) {
        int nn = p * 4 + rw;
        Wt[(size_t)(n0 + nn) * K + k0 + cl] = T[nn][cl];       // coalesced in k
    }
}

// -------- gather + LayerNorm1, per (b, image-row hs), coalesced ------------
__global__ __launch_bounds__(256) void k_ln1(const float* __restrict__ x,
                                             const float* __restrict__ g,
                                             const float* __restrict__ bt,
                                             unsigned short* __restrict__ ln1) {
    int blk = blockIdx.x;           // b*64 + hs
    int b  = blk >> 6, hs = blk & 63;
    int t  = threadIdx.x;
    int w  = t & 63, cg = t >> 6;   // pixel, channel-group (4)
    const float* row = x + (size_t)b * DIM * 4096 + hs * 64;

    float sum = 0.f, sq = 0.f;
    for (int i = 0; i < 96; i++) {
        int c = i * 4 + cg;
        float v = row[(size_t)c * 4096 + w];
        sum += v; sq += v * v;
    }
    __shared__ float red[2][4][64];
    __shared__ float mean_s[64], rstd_s[64];
    red[0][cg][w] = sum; red[1][cg][w] = sq;
    __syncthreads();
    if (t < 64) {
        float s  = red[0][0][t] + red[0][1][t] + red[0][2][t] + red[0][3][t];
        float q2 = red[1][0][t] + red[1][1][t] + red[1][2][t] + red[1][3][t];
        float mean = s * (1.0f / DIM);
        float var  = q2 * (1.0f / DIM) - mean * mean;
        mean_s[t] = mean;
        rstd_s[t] = rsqrtf(var + 1e-5f);
    }
    __syncthreads();

    int wp = t >> 2, seg = t & 3;
    int hr = (hs + 60) & 63, wr = (wp + 60) & 63;
    int tok = ((b * 8 + (hr >> 3)) * 8 + (wr >> 3)) * 64 + (hr & 7) * 8 + (wr & 7);

    __shared__ __align__(16) unsigned short tile[64][72];
    for (int chunk = 0; chunk < 6; chunk++) {
        float mean = mean_s[w], rstd = rstd_s[w];
        #pragma unroll
        for (int it = 0; it < 16; it++) {
            int cl = it * 4 + cg;
            int c  = chunk * 64 + cl;
            float v = row[(size_t)c * 4096 + w];
            tile[w][cl] = f2bf((v - mean) * rstd * g[c] + bt[c]);
        }
        __syncthreads();
        u16x8 v0 = *(const u16x8*)&tile[wp][seg * 16];
        u16x8 v1 = *(const u16x8*)&tile[wp][seg * 16 + 8];
        unsigned short* op = ln1 + (size_t)tok * DIM + chunk * 64 + seg * 16;
        *(u16x8*)op = v0;
        *(u16x8*)(op + 8) = v1;
        __syncthreads();
    }
}

// ---------------- wave-private MFMA GEMM: C[M,N] = A[M,K] * Bt[N,K]^T + bias
// 1 block = 1 wave (64 threads) owning a 64x64 output tile with PRIVATE
// ring-2 LDS staging. ZERO s_barrier: each wave issues its own 8
// global_load_lds per BK=32 step, waits vmcnt(8) on its OWN loads, reads
// its private region, 16 MFMAs. 17.4KB LDS -> 9 blocks/CU; de-phased
// independent waves replace barrier-coupled lockstep (R0-R8 ledger: every
// barriered variant 91-136us; waves stalled ~90% at barriers).
// MFMA operand values & accumulation order bit-identical to prior rounds.
// EPI: 0 bias->bf16; 1 bias+gelu->bf16;
//      2 bias+residual gather->f32 rows stored PIXEL-RASTER;
//      3 bias->f32; 4 bias->bf16 scattered to [qkv][head][tok][48];
//      5 bias->f32, M pixel-raster, direct out[b][c][hs][ws] full-line runs
template <int EPI>
__global__ __launch_bounds__(64) void k_gemm_wave(
        const unsigned short* __restrict__ A,
        const unsigned short* __restrict__ Bt,
        const float* __restrict__ bias,
        void* __restrict__ Cout,
        const float* __restrict__ xres,
        int N, int K, int GX) {
    // ring-2 staging: buf b at u16 [b*4096]: A koct j @ j*512, B @ 2048+j*512.
    // epilogue bounce reuses SH: bf16 [64][68] u16; EPI5 [64][65] f32.
    __shared__ __align__(16) unsigned short SH[8704];   // 17408 B
    int lane = threadIdx.x;
    int quad = lane >> 4, l15 = lane & 15;

    int l   = blockIdx.x;
    int xcd = l & 7;
    int r_  = l >> 3;
    int bx  = r_ % GX;
    int by  = (r_ / GX) * 8 + xcd;
    int m0 = by * 64, n0 = bx * 64;

    const unsigned short* gA = A  + (size_t)(m0 + lane) * K;
    const unsigned short* gB = Bt + (size_t)(n0 + lane) * K;
    int k0 = 0;

    auto stage = [&](int buf) {
        #pragma unroll
        for (int j = 0; j < 4; j++)
            __builtin_amdgcn_global_load_lds(
                (const __attribute__((address_space(1))) void*)(gA + k0 + j * 8),
                (__attribute__((address_space(3))) void*)&SH[buf * 4096 + j * 512],
                16, 0, 0);
        #pragma unroll
        for (int j = 0; j < 4; j++)
            __builtin_amdgcn_global_load_lds(
                (const __attribute__((address_space(1))) void*)(gB + k0 + j * 8),
                (__attribute__((address_space(3))) void*)&SH[buf * 4096 + 2048 + j * 512],
                16, 0, 0);
        k0 += 32;
    };

    f32x4 acc[4][4] = {};
    int nsteps = K >> 5;

    stage(0);
    for (int t = 0; t < nsteps; ++t) {
        int cur = t & 1;
        if (t + 1 < nsteps) {
            stage(cur ^ 1);
            // own step-t loads (oldest 8) landed; 8 just-issued stay in flight
            asm volatile("s_waitcnt vmcnt(8)" ::: "memory");
        } else {
            asm volatile("s_waitcnt vmcnt(0)" ::: "memory");
        }
        bf16x8 af[4], bfr[4];
        #pragma unroll
        for (int r = 0; r < 4; r++)
            af[r] = *(const bf16x8*)&SH[cur * 4096 + quad * 512 + (r * 16 + l15) * 8];
        #pragma unroll
        for (int r2 = 0; r2 < 4; r2++)
            bfr[r2] = *(const bf16x8*)&SH[cur * 4096 + 2048 + quad * 512 + (r2 * 16 + l15) * 8];
        #pragma unroll
        for (int r = 0; r < 4; r++)
            #pragma unroll
            for (int r2 = 0; r2 < 4; r2++)
                acc[r][r2] = __builtin_amdgcn_mfma_f32_16x16x32_bf16(
                                 af[r], bfr[r2], acc[r][r2], 0, 0, 0);
    }

    if constexpr (EPI == 2 || EPI == 3) {
        // f32 direct: 16 lanes x 4B = full 64B lines
        #pragma unroll
        for (int r2 = 0; r2 < 4; r2++) {
            int n = n0 + r2 * 16 + l15;
            float bn = bias[n];
            #pragma unroll
            for (int r = 0; r < 4; r++) {
                #pragma unroll
                for (int reg = 0; reg < 4; reg++) {
                    int m = m0 + r * 16 + quad * 4 + reg;
                    float v = acc[r][r2][reg] + bn;
                    if (EPI == 2) {
                        int b, hs, ws_;
                        tok2src(m, b, hs, ws_);
                        v += xres[(((size_t)b * DIM + n) * 64 + hs) * 64 + ws_];
                        int p = (b * 64 + hs) * 64 + ws_;   // pixel-raster row
                        ((float*)Cout)[(size_t)p * N + n] = v;
                    } else {
                        ((float*)Cout)[(size_t)m * N + n] = v;
                    }
                }
            }
        }
    } else if constexpr (EPI == 5) {
        // M pixel-raster: m0 64-aligned => tile = one image row (b,hs), ws 0..63.
        // Bounce [c][ws] f32 -> each output c-row stored as one 256B run.
        float* SF = (float*)SH;              // [64][65] f32 = 16640 B
        int b  = m0 >> 12;
        int hs = (m0 >> 6) & 63;
        #pragma unroll
        for (int r2 = 0; r2 < 4; r2++) {
            int c = r2 * 16 + l15;
            float bn = bias[n0 + c];
            #pragma unroll
            for (int r = 0; r < 4; r++) {
                f32x4 v4;
                #pragma unroll
                for (int reg = 0; reg < 4; reg++)
                    v4[reg] = acc[r][r2][reg] + bn;
                *(f32x4*)&SF[c * 65 + r * 16 + quad * 4] = v4;   // ws index
            }
        }
        #pragma unroll
        for (int i = 0; i < 16; i++) {
            int id = i * 64 + lane;          // [0,1024): c = id>>4, ch = id&15
            int c  = id >> 4, ch = id & 15;
            f32x4 v = *(const f32x4*)&SF[c * 65 + ch * 4];
            float* dst = (float*)Cout + ((size_t)(b * DIM + n0 + c) * 64 + hs) * 64;
            *(f32x4*)&dst[ch * 4] = v;       // 16 lanes = full 256B run
        }
    } else {
        // bf16: bounce [64][68] u16, read back 128B-contiguous rows.
        #pragma unroll
        for (int r2 = 0; r2 < 4; r2++) {
            int col = r2 * 16 + l15;
            float bn = bias[n0 + col];
            #pragma unroll
            for (int r = 0; r < 4; r++) {
                int row0 = r * 16 + quad * 4;
                #pragma unroll
                for (int reg = 0; reg < 4; reg++) {
                    float v = acc[r][r2][reg] + bn;
                    if (EPI == 1) v = gelu(v);
                    SH[(row0 + reg) * 68 + col] = f2bf(v);
                }
            }
        }
        #pragma unroll
        for (int i = 0; i < 8; i++) {
            int m  = i * 8 + (lane >> 3);    // 8 rows / iteration
            int ch = lane & 7;
            u16x8 v = *(const u16x8*)&SH[m * 68 + ch * 8];
            if (EPI == 4) {
                int n = n0 + ch * 8;
                int qi  = n / 384;
                int rem = n - qi * 384;
                int hh  = rem / 48;
                int d   = rem - hh * 48;     // 8-chunks never cross 48-boundary
                *(u16x8*)&((unsigned short*)Cout)[((size_t)(qi * 8 + hh) * NTOK + m0 + m) * 48 + d] = v;
            } else {
                *(u16x8*)&((unsigned short*)Cout)[(size_t)(m0 + m) * N + n0 + ch * 8] = v;
            }
        }
    }
}

// ---------------- MFMA attention: 1 block = 1 window, 4 waves x 2 heads -----
// qkvh layout: [qkv(3)][head(8)][tok(32768)][48] bf16.
__global__ __launch_bounds__(256) void k_attn_mfma(
        const unsigned short* __restrict__ qkvh,
        unsigned short* __restrict__ attn) {
    // per-wave LDS: VT [48][72] (3456 u16) + P [64][72] (4608 u16) = 8064 u16
    __shared__ __align__(16) unsigned short lds[4][8064];   // 64512 B total
    int tid  = threadIdx.x;
    int lane = tid & 63;
    int wave = tid >> 6;
    int quad = lane >> 4, l15 = lane & 15;
    int win  = blockIdx.x;
    int tok0 = win * 64;
    unsigned short* VT = &lds[wave][0];
    unsigned short* P  = &lds[wave][3456];
    const float scale = 0.14433756729740643f;  // 48^-0.5

    for (int hi = 0; hi < 2; hi++) {
        int h = wave + hi * 4;
        const unsigned short* qb = qkvh + ((size_t)(0 * 8 + h) * NTOK + tok0) * 48;
        const unsigned short* kb = qkvh + ((size_t)(1 * 8 + h) * NTOK + tok0) * 48;
        const unsigned short* vb = qkvh + ((size_t)(2 * 8 + h) * NTOK + tok0) * 48;

        // stage V^T into LDS: lane = token, write column `lane`
        #pragma unroll
        for (int i = 0; i < 6; i++) {
            u16x8 v = *(const u16x8*)&vb[lane * 48 + i * 8];
            #pragma unroll
            for (int j = 0; j < 8; j++)
                VT[(i * 8 + j) * 72 + lane] = v[j];
        }

        // K fragments (B-operand of QK^T): kf[ni][chunk]
        bf16x8 kf[4][2];
        #pragma unroll
        for (int ni = 0; ni < 4; ni++) {
            kf[ni][0] = *(const bf16x8*)&kb[(ni * 16 + l15) * 48 + quad * 8];
            bf16x8 z = {};
            if (quad < 2)
                z = *(const bf16x8*)&kb[(ni * 16 + l15) * 48 + 32 + quad * 8];
            kf[ni][1] = z;   // d in [48,64) zero-masked
        }

        // S = Q K^T   (64x64, K=48 padded to 64 with zeros)
        f32x4 sacc[4][4] = {};
        #pragma unroll
        for (int mi = 0; mi < 4; mi++) {
            bf16x8 qf0 = *(const bf16x8*)&qb[(mi * 16 + l15) * 48 + quad * 8];
            bf16x8 qf1 = {};
            if (quad < 2)
                qf1 = *(const bf16x8*)&qb[(mi * 16 + l15) * 48 + 32 + quad * 8];
            #pragma unroll
            for (int ni = 0; ni < 4; ni++) {
                sacc[mi][ni] = __builtin_amdgcn_mfma_f32_16x16x32_bf16(qf0, kf[ni][0], sacc[mi][ni], 0, 0, 0);
                sacc[mi][ni] = __builtin_amdgcn_mfma_f32_16x16x32_bf16(qf1, kf[ni][1], sacc[mi][ni], 0, 0, 0);
            }
        }

        // softmax over rows (C-layout: row=quad*4+reg, col=ni*16+l15), P -> LDS
        #pragma unroll
        for (int mi = 0; mi < 4; mi++) {
            #pragma unroll
            for (int reg = 0; reg < 4; reg++) {
                float s0 = sacc[mi][0][reg] * scale;
                float s1 = sacc[mi][1][reg] * scale;
                float s2 = sacc[mi][2][reg] * scale;
                float s3 = sacc[mi][3][reg] * scale;
                float mx = fmaxf(fmaxf(s0, s1), fmaxf(s2, s3));
                #pragma unroll
                for (int off = 1; off < 16; off <<= 1)
                    mx = fmaxf(mx, __shfl_xor(mx, off));
                float e0 = __expf(s0 - mx);
                float e1 = __expf(s1 - mx);
                float e2 = __expf(s2 - mx);
                float e3 = __expf(s3 - mx);
                float sm = e0 + e1 + e2 + e3;
                #pragma unroll
                for (int off = 1; off < 16; off <<= 1)
                    sm += __shfl_xor(sm, off);
                float inv = 1.0f / sm;
                int row = mi * 16 + quad * 4 + reg;
                P[row * 72 +  0 + l15] = f2bf(e0 * inv);
                P[row * 72 + 16 + l15] = f2bf(e1 * inv);
                P[row * 72 + 32 + l15] = f2bf(e2 * inv);
                P[row * 72 + 48 + l15] = f2bf(e3 * inv);
            }
        }

        // O = P V   (64x48, K=64); V^T fragments from LDS
        bf16x8 vf[3][2];
        #pragma unroll
        for (int ni = 0; ni < 3; ni++)
            #pragma unroll
            for (int kt = 0; kt < 2; kt++)
                vf[ni][kt] = *(const bf16x8*)&VT[(ni * 16 + l15) * 72 + kt * 32 + quad * 8];

        #pragma unroll
        for (int mi = 0; mi < 4; mi++) {
            bf16x8 pf0 = *(const bf16x8*)&P[(mi * 16 + l15) * 72 + quad * 8];
            bf16x8 pf1 = *(const bf16x8*)&P[(mi * 16 + l15) * 72 + 32 + quad * 8];
            f32x4 o[3] = {};
            #pragma unroll
            for (int ni = 0; ni < 3; ni++) {
                o[ni] = __builtin_amdgcn_mfma_f32_16x16x32_bf16(pf0, vf[ni][0], o[ni], 0, 0, 0);
                o[ni] = __builtin_amdgcn_mfma_f32_16x16x32_bf16(pf1, vf[ni][1], o[ni], 0, 0, 0);
            }
            #pragma unroll
            for (int ni = 0; ni < 3; ni++)
                #pragma unroll
                for (int reg = 0; reg < 4; reg++) {
                    int tok = tok0 + mi * 16 + quad * 4 + reg;
                    attn[(size_t)tok * DIM + h * HD + ni * 16 + l15] = f2bf(o[ni][reg]);
                }
        }
    }
}

// ---------------- LayerNorm2 over y (f32) -> ln2 (bf16), row-order agnostic --
__global__ __launch_bounds__(64) void k_ln2(const float* __restrict__ y,
                                            const float* __restrict__ g,
                                            const float* __restrict__ bt,
                                            unsigned short* __restrict__ out) {
    int tok = blockIdx.x;
    int t   = threadIdx.x;
    const float* row = y + (size_t)tok * DIM;
    float v[6];
    float sum = 0.f, sq = 0.f;
    #pragma unroll
    for (int i = 0; i < 6; i++) {
        v[i] = row[i * 64 + t];
        sum += v[i]; sq += v[i] * v[i];
    }
    #pragma unroll
    for (int o = 32; o > 0; o >>= 1) {
        sum += __shfl_xor(sum, o, 64);
        sq  += __shfl_xor(sq, o, 64);
    }
    float mean = sum * (1.0f / DIM);
    float var  = sq * (1.0f / DIM) - mean * mean;
    float rstd = rsqrtf(var + 1e-5f);
    unsigned short* orow = out + (size_t)tok * DIM;
    #pragma unroll
    for (int i = 0; i < 6; i++) {
        int c = i * 64 + t;
        orow[c] = f2bf((v[i] - mean) * rstd * g[c] + bt[c]);
    }
}

extern "C" void kernel_launch(void* const* d_in, const int* in_sizes, int n_in,
                              void* d_out, int out_size, void* d_ws, size_t ws_size,
                              hipStream_t stream) {
    const float* x      = (const float*)d_in[0];
    const float* qkv_w  = (const float*)d_in[1];
    const float* qkv_b  = (const float*)d_in[2];
    const float* proj_w = (const float*)d_in[3];
    const float* proj_b = (const float*)d_in[4];
    const float* ln1_g  = (const float*)d_in[5];
    const float* ln1_b  = (const float*)d_in[6];
    const float* ln2_g  = (const float*)d_in[7];
    const float* ln2_b  = (const float*)d_in[8];
    const float* w1     = (const float*)d_in[9];
    const float* b1     = (const float*)d_in[10];
    const float* w2     = (const float*)d_in[11];
    const float* b2     = (const float*)d_in[12];

    char* ws = (char*)d_ws;
    unsigned short* qkv_wt  = (unsigned short*)(ws + 0);
    unsigned short* proj_wt = (unsigned short*)(ws + 884736);
    unsigned short* w1t     = (unsigned short*)(ws + 1179648);
    unsigned short* w2t     = (unsigned short*)(ws + 2359296);
    unsigned short* ln1     = (unsigned short*)(ws + 4194304);
    unsigned short* qkv     = (unsigned short*)(ws + 29360128);   // [3][8][32768][48]
    unsigned short* attn    = (unsigned short*)(ws + 104857600);
    float*          y       = (float*)(ws + 130023424);  // rows = pixel-raster
    unsigned short* ln2     = ln1;
    unsigned short* mid     = qkv;      // [32768][1536] bf16, rows = pixel-raster

    k_wt4<<<432, 256, 0, stream>>>(qkv_w, proj_w, w1, w2, qkv_wt, proj_wt, w1t, w2t);
    k_ln1<<<512, 256, 0, stream>>>(x, ln1_g, ln1_b, ln1);
    k_gemm_wave<4><<<512 * 18, 64, 0, stream>>>(ln1, qkv_wt, qkv_b, qkv, nullptr, 1152, 384, 18);
    k_attn_mfma<<<NWIN, 256, 0, stream>>>(qkv, attn);
    k_gemm_wave<2><<<512 * 6, 64, 0, stream>>>(attn, proj_wt, proj_b, y, x, 384, 384, 6);
    k_ln2<<<NTOK, 64, 0, stream>>>(y, ln2_g, ln2_b, ln2);
    k_gemm_wave<1><<<512 * 24, 64, 0, stream>>>(ln2, w1t, b1, mid, nullptr, 1536, 384, 24);
    k_gemm_wave<5><<<512 * 6, 64, 0, stream>>>(mid, w2t, b2, (float*)d_out, nullptr, 384, 1536, 6);
}

// Round 10
// 425.188 us; speedup vs baseline: 1.9229x; 1.9229x over previous
//
#include <hip/hip_runtime.h>
#include <hip/hip_bf16.h>
#include <math.h>

#define DIM   384
#define HEADS 8
#define HD    48
#define NTOK  32768   // 8 * 64 * 64
#define NWIN  512     // 8 images * 64 windows

typedef __attribute__((ext_vector_type(8))) short bf16x8;
typedef __attribute__((ext_vector_type(8))) unsigned short u16x8;
typedef __attribute__((ext_vector_type(4))) float f32x4;

__device__ __forceinline__ float bf2f(unsigned short u) {
    unsigned int v = ((unsigned int)u) << 16;
    return __uint_as_float(v);
}
// RNE f32->bf16 via native cast (proven bit-identical in R5-R9 bench)
__device__ __forceinline__ unsigned short f2bf(float f) {
    __bf16 b = (__bf16)f;
    return __builtin_bit_cast(unsigned short, b);
}

// branchless erf-based GELU (A&S 7.1.25 3-term, |err_erf| < 2.5e-5 << bf16 ulp)
__device__ __forceinline__ float gelu(float v) {
    float z  = v * 0.70710678118654752f;
    float az = fabsf(z);
    float t  = __builtin_amdgcn_rcpf(1.0f + 0.47047f * az);
    float p  = t * (0.3480242f + t * (-0.0958798f + t * 0.7478556f));
    float ea = 1.0f - p * __expf(-az * az);
    float er = copysignf(ea, z);
    return 0.5f * v * (1.0f + er);
}

// token (window order) -> source pixel of x (accounting for roll by -SHIFT)
__device__ __forceinline__ void tok2src(int tok, int& b, int& hs, int& ws) {
    int bb  = tok >> 12;
    int win = (tok >> 6) & 63;
    int t   = tok & 63;
    int hi = win >> 3, wi = win & 7;
    int r  = t >> 3,  cc = t & 7;
    b  = bb;
    hs = (hi * 8 + r  + 4) & 63;
    ws = (wi * 8 + cc + 4) & 63;
}

// ------------- weight convert f32 [K][N] -> bf16 [N][K], coalesced both
// sides via 64x64 LDS tile transpose. One block = one 64x64 tile.
__global__ __launch_bounds__(256) void k_wt4(const float* __restrict__ qkv_w,
                                             const float* __restrict__ proj_w,
                                             const float* __restrict__ w1,
                                             const float* __restrict__ w2,
                                             unsigned short* __restrict__ d0,
                                             unsigned short* __restrict__ d1,
                                             unsigned short* __restrict__ d2,
                                             unsigned short* __restrict__ d3) {
    // tiles: qkv 6x18=108 | proj 6x6=36 | w1 6x24=144 | w2 24x6=144  => 432
    __shared__ unsigned short T[64][66];
    int b = blockIdx.x;
    const float* W; unsigned short* Wt; int K, N, lt;
    if (b < 108)      { W = qkv_w;  Wt = d0; K = 384;  N = 1152; lt = b; }
    else if (b < 144) { W = proj_w; Wt = d1; K = 384;  N = 384;  lt = b - 108; }
    else if (b < 288) { W = w1;     Wt = d2; K = 384;  N = 1536; lt = b - 144; }
    else              { W = w2;     Wt = d3; K = 1536; N = 384;  lt = b - 288; }
    int tn = N >> 6;
    int k0 = (lt / tn) << 6, n0 = (lt % tn) << 6;
    int t  = threadIdx.x;
    int cl = t & 63, rw = t >> 6;
    #pragma unroll
    for (int p = 0; p < 16; p++) {
        int kk = p * 4 + rw;
        T[cl][kk] = f2bf(W[(size_t)(k0 + kk) * N + n0 + cl]);  // coalesced in n
    }
    __syncthreads();
    #pragma unroll
    for (int p = 0; p < 16; p++) {
        int nn = p * 4 + rw;
        Wt[(size_t)(n0 + nn) * K + k0 + cl] = T[nn][cl];       // coalesced in k
    }
}

// -------- gather + LayerNorm1, SINGLE-PASS (96 values held in registers;
// deletes the second 100MB read of x), per (b, image-row hs), coalesced ----
__global__ __launch_bounds__(256) void k_ln1(const float* __restrict__ x,
                                             const float* __restrict__ g,
                                             const float* __restrict__ bt,
                                             unsigned short* __restrict__ ln1) {
    int blk = blockIdx.x;           // b*64 + hs
    int b  = blk >> 6, hs = blk & 63;
    int t  = threadIdx.x;
    int w  = t & 63, cg = t >> 6;   // pixel, channel-group (4)
    const float* row = x + (size_t)b * DIM * 4096 + hs * 64;

    float v[96];
    float sum = 0.f, sq = 0.f;
    #pragma unroll
    for (int i = 0; i < 96; i++) {
        int c = i * 4 + cg;
        float xv = row[(size_t)c * 4096 + w];
        v[i] = xv;
        sum += xv; sq += xv * xv;
    }
    __shared__ float red[2][4][64];
    __shared__ float mean_s[64], rstd_s[64];
    red[0][cg][w] = sum; red[1][cg][w] = sq;
    __syncthreads();
    if (t < 64) {
        float s  = red[0][0][t] + red[0][1][t] + red[0][2][t] + red[0][3][t];
        float q2 = red[1][0][t] + red[1][1][t] + red[1][2][t] + red[1][3][t];
        float mean = s * (1.0f / DIM);
        float var  = q2 * (1.0f / DIM) - mean * mean;
        mean_s[t] = mean;
        rstd_s[t] = rsqrtf(var + 1e-5f);
    }
    __syncthreads();

    int wp = t >> 2, seg = t & 3;
    int hr = (hs + 60) & 63, wr = (wp + 60) & 63;
    int tok = ((b * 8 + (hr >> 3)) * 8 + (wr >> 3)) * 64 + (hr & 7) * 8 + (wr & 7);

    __shared__ __align__(16) unsigned short tile[64][72];
    #pragma unroll
    for (int chunk = 0; chunk < 6; chunk++) {
        float mean = mean_s[w], rstd = rstd_s[w];
        #pragma unroll
        for (int it = 0; it < 16; it++) {
            int cl = it * 4 + cg;
            int c  = chunk * 64 + cl;
            tile[w][cl] = f2bf((v[chunk * 16 + it] - mean) * rstd * g[c] + bt[c]);
        }
        __syncthreads();
        u16x8 v0 = *(const u16x8*)&tile[wp][seg * 16];
        u16x8 v1 = *(const u16x8*)&tile[wp][seg * 16 + 8];
        unsigned short* op = ln1 + (size_t)tok * DIM + chunk * 64 + seg * 16;
        *(u16x8*)op = v0;
        *(u16x8*)(op + 8) = v1;
        __syncthreads();
    }
}

// ---------------- MFMA GEMM: C[M,N] = A[M,K](bf16) * Bt[N,K]^T(bf16) + bias
// 128x128 tile, 4 waves, 4x4 16x16x32 MFMA.
// BK=32, ring-3 LDS staging, prefetch depth 2 with counted vmcnt(8)
// (R3/R7-proven structure). K is a TEMPLATE parameter and the ring is
// unrolled by its period 3, so every CUR/NXT is a literal: all ds_read /
// global_load_lds addresses constant-fold to base+imm (attacks VALUBusy 47%).
// Instruction semantics identical to R7.
// bf16 epilogues (EPI 0/1/4) bounce the C-tile through LDS (XOR-swizzled)
// so all HBM writes are full-line u16x8.
// EPI: 0 bias->bf16; 1 bias+gelu->bf16;
//      2 bias+residual gather->f32 rows stored PIXEL-RASTER;
//      3 bias->f32; 4 bias->bf16 scattered to [qkv][head][tok][48];
//      5 bias->f32, M pixel-raster, direct out[b][c][hs][ws] full-line runs
template <int EPI, int K>
__global__ __launch_bounds__(256) void k_gemm_mfma(
        const unsigned short* __restrict__ A,
        const unsigned short* __restrict__ Bt,
        const float* __restrict__ bias,
        void* __restrict__ Cout,
        const float* __restrict__ xres,
        int N, int GX) {
    // staging: A bufs [3][4096] u16 at 0; B bufs [3][4096] u16 at 12288.
    // bounce views (after K-loop, reuse SH):
    //   bf16 EPIs: [128][136] u16 (34816 B); EPI5: [128][68] f32 (34816 B)
    __shared__ __align__(16) unsigned short SH[24576];   // 48 KB
    int tid  = threadIdx.x;
    int lane = tid & 63;
    int wave = tid >> 6;
    int wm = wave >> 1, wn = wave & 1;
    int quad = lane >> 4, l15 = lane & 15;

    int l   = blockIdx.x;
    int xcd = l & 7;
    int r_  = l >> 3;
    int bx  = r_ % GX;
    int by  = (r_ / GX) * 8 + xcd;
    int m0 = by * 128, n0 = bx * 128;

    const unsigned short* gA0 = A  + (size_t)(m0 +      lane) * K + wave * 8;
    const unsigned short* gA1 = A  + (size_t)(m0 + 64 + lane) * K + wave * 8;
    const unsigned short* gB0 = Bt + (size_t)(n0 +      lane) * K + wave * 8;
    const unsigned short* gB1 = Bt + (size_t)(n0 + 64 + lane) * K + wave * 8;

    auto stage = [&](int buf) {
        __builtin_amdgcn_global_load_lds(
            (const __attribute__((address_space(1))) void*)gA0,
            (__attribute__((address_space(3))) void*)&SH[buf * 4096 + wave * 1024],
            16, 0, 0);
        __builtin_amdgcn_global_load_lds(
            (const __attribute__((address_space(1))) void*)gA1,
            (__attribute__((address_space(3))) void*)&SH[buf * 4096 + wave * 1024 + 512],
            16, 0, 0);
        __builtin_amdgcn_global_load_lds(
            (const __attribute__((address_space(1))) void*)gB0,
            (__attribute__((address_space(3))) void*)&SH[12288 + buf * 4096 + wave * 1024],
            16, 0, 0);
        __builtin_amdgcn_global_load_lds(
            (const __attribute__((address_space(1))) void*)gB1,
            (__attribute__((address_space(3))) void*)&SH[12288 + buf * 4096 + wave * 1024 + 512],
            16, 0, 0);
        gA0 += 32; gA1 += 32; gB0 += 32; gB1 += 32;   // advance one BK=32 step
    };

    f32x4 acc[4][4] = {};
    constexpr int NSTEPS = K >> 5;      // 12 or 48, multiple of 3
    constexpr int U = NSTEPS / 3;

    int oa = (quad * 128 + wm * 64 + l15) * 8;           // A frag base (u16)
    int ob = 12288 + (quad * 128 + wn * 64 + l15) * 8;   // B frag base (u16)

    stage(0);
    stage(1);

// one K-step with literal ring indices. MODE: 0=stage(NXT)+vmcnt(8),
// 1=vmcnt(4) no stage, 2=vmcnt(0) no stage. Semantics identical to R7 loop.
#define GSTEP(CUR, NXT, MODE)                                                \
    {                                                                        \
        __builtin_amdgcn_s_barrier();                                        \
        if constexpr ((MODE) == 0) {                                         \
            stage(NXT);                                                      \
            asm volatile("s_waitcnt vmcnt(8)" ::: "memory");                 \
        } else if constexpr ((MODE) == 1) {                                  \
            asm volatile("s_waitcnt vmcnt(4)" ::: "memory");                 \
        } else {                                                             \
            asm volatile("s_waitcnt vmcnt(0)" ::: "memory");                 \
        }                                                                    \
        __builtin_amdgcn_s_barrier();                                        \
        bf16x8 af[4], bfr[4];                                                \
        _Pragma("unroll")                                                    \
        for (int r = 0; r < 4; r++)                                          \
            af[r] = *(const bf16x8*)&SH[(CUR) * 4096 + oa + r * 128];        \
        _Pragma("unroll")                                                    \
        for (int r2 = 0; r2 < 4; r2++)                                       \
            bfr[r2] = *(const bf16x8*)&SH[(CUR) * 4096 + ob + r2 * 128];     \
        _Pragma("unroll")                                                    \
        for (int r = 0; r < 4; r++)                                          \
            _Pragma("unroll")                                                \
            for (int r2 = 0; r2 < 4; r2++)                                   \
                acc[r][r2] = __builtin_amdgcn_mfma_f32_16x16x32_bf16(        \
                                 af[r], bfr[r2], acc[r][r2], 0, 0, 0);       \
    }

    #pragma unroll 1
    for (int u = 0; u < U - 1; ++u) {
        GSTEP(0, 2, 0)
        GSTEP(1, 0, 0)
        GSTEP(2, 1, 0)
    }
    // final triple: t = NSTEPS-3 (stages last buffer), NSTEPS-2, NSTEPS-1
    GSTEP(0, 2, 0)
    GSTEP(1, 0, 1)
    GSTEP(2, 0, 2)
#undef GSTEP

    if constexpr (EPI == 2 || EPI == 3) {
        // f32 outputs: 16 lanes x 4B = full 64B lines already
        #pragma unroll
        for (int r2 = 0; r2 < 4; r2++) {
            int n = n0 + wn * 64 + r2 * 16 + l15;
            float bn = bias[n];
            #pragma unroll
            for (int r = 0; r < 4; r++) {
                #pragma unroll
                for (int reg = 0; reg < 4; reg++) {
                    int m = m0 + wm * 64 + r * 16 + quad * 4 + reg;
                    float v = acc[r][r2][reg] + bn;
                    if (EPI == 2) {
                        int b, hs, ws_;
                        tok2src(m, b, hs, ws_);
                        v += xres[(((size_t)b * DIM + n) * 64 + hs) * 64 + ws_];
                        int p = (b * 64 + hs) * 64 + ws_;   // pixel-raster row
                        ((float*)Cout)[(size_t)p * N + n] = v;
                    } else {
                        ((float*)Cout)[(size_t)m * N + n] = v;
                    }
                }
            }
        }
    } else if constexpr (EPI == 5) {
        // M is pixel-raster: tile = 2 image rows (hs0, hs0+1) x 64 ws of
        // image b. Bounce [c][ws] f32 -> full-line aligned ws-runs.
        float* SF = (float*)SH;              // [128][68] f32 = 34816 B
        __syncthreads();                     // staging reads done
        int b   = m0 >> 12;
        int hs0 = (m0 >> 6) & 63;
        #pragma unroll
        for (int h2 = 0; h2 < 2; h2++) {
            if (wm == h2) {
                #pragma unroll
                for (int r2 = 0; r2 < 4; r2++) {
                    int c = wn * 64 + r2 * 16 + l15;
                    float bn = bias[n0 + c];
                    #pragma unroll
                    for (int r = 0; r < 4; r++) {
                        f32x4 v4;
                        #pragma unroll
                        for (int reg = 0; reg < 4; reg++)
                            v4[reg] = acc[r][r2][reg] + bn;
                        *(f32x4*)&SF[c * 68 + r * 16 + quad * 4] = v4;  // ws = r*16+quad*4+reg
                    }
                }
            }
            __syncthreads();
            #pragma unroll
            for (int i = 0; i < 8; i++) {
                int id = tid + i * 256;          // [0,2048): c = id>>4, chunk = id&15
                int c  = id >> 4, ch = id & 15;
                f32x4 v = *(const f32x4*)&SF[c * 68 + ch * 4];
                float* dst = (float*)Cout + ((size_t)(b * DIM + n0 + c) * 64 + hs0 + h2) * 64;
                *(f32x4*)&dst[ch * 4] = v;       // 16 consecutive threads = 256B run
            }
            __syncthreads();
        }
    } else {
        // bf16 outputs: bounce through LDS for full-line coalesced stores.
        // XOR-swizzle (32B toggle on row bit 3) -> quads hit disjoint banks.
        __syncthreads();   // all waves done reading staging LDS
        #pragma unroll
        for (int r2 = 0; r2 < 4; r2++) {
            int col = wn * 64 + r2 * 16 + l15;
            float bn = bias[n0 + col];
            #pragma unroll
            for (int r = 0; r < 4; r++) {
                int row0 = wm * 64 + r * 16 + quad * 4;
                #pragma unroll
                for (int reg = 0; reg < 4; reg++) {
                    int row = row0 + reg;
                    float v = acc[r][r2][reg] + bn;
                    if (EPI == 1) v = gelu(v);
                    SH[(row * 136 + col) ^ (((row >> 3) & 1) << 4)] = f2bf(v);
                }
            }
        }
        __syncthreads();
        #pragma unroll
        for (int i = 0; i < 8; i++) {
            int chunk = tid + i * 256;        // [0, 2048)
            int m = chunk >> 4, nc = chunk & 15;
            int idx = (m * 136 + nc * 8) ^ (((m >> 3) & 1) << 4);
            u16x8 v = *(const u16x8*)&SH[idx];
            if (EPI == 4) {
                int n = n0 + nc * 8;
                int qi  = n / 384;
                int rem = n - qi * 384;
                int hh  = rem / 48;
                int d   = rem - hh * 48;      // 8-chunks never cross 48-boundary
                *(u16x8*)&((unsigned short*)Cout)[((size_t)(qi * 8 + hh) * NTOK + m0 + m) * 48 + d] = v;
            } else {
                *(u16x8*)&((unsigned short*)Cout)[(size_t)(m0 + m) * N + n0 + nc * 8] = v;
            }
        }
    }
}

// ---------------- MFMA attention: 1 block = 1 window, 4 waves x 2 heads -----
// qkvh layout: [qkv(3)][head(8)][tok(32768)][48] bf16.
__global__ __launch_bounds__(256) void k_attn_mfma(
        const unsigned short* __restrict__ qkvh,
        unsigned short* __restrict__ attn) {
    // per-wave LDS: VT [48][72] (3456 u16) + P [64][72] (4608 u16) = 8064 u16
    __shared__ __align__(16) unsigned short lds[4][8064];   // 64512 B total
    int tid  = threadIdx.x;
    int lane = tid & 63;
    int wave = tid >> 6;
    int quad = lane >> 4, l15 = lane & 15;
    int win  = blockIdx.x;
    int tok0 = win * 64;
    unsigned short* VT = &lds[wave][0];
    unsigned short* P  = &lds[wave][3456];
    const float scale = 0.14433756729740643f;  // 48^-0.5

    for (int hi = 0; hi < 2; hi++) {
        int h = wave + hi * 4;
        const unsigned short* qb = qkvh + ((size_t)(0 * 8 + h) * NTOK + tok0) * 48;
        const unsigned short* kb = qkvh + ((size_t)(1 * 8 + h) * NTOK + tok0) * 48;
        const unsigned short* vb = qkvh + ((size_t)(2 * 8 + h) * NTOK + tok0) * 48;

        // stage V^T into LDS: lane = token, write column `lane`
        #pragma unroll
        for (int i = 0; i < 6; i++) {
            u16x8 v = *(const u16x8*)&vb[lane * 48 + i * 8];
            #pragma unroll
            for (int j = 0; j < 8; j++)
                VT[(i * 8 + j) * 72 + lane] = v[j];
        }

        // K fragments (B-operand of QK^T): kf[ni][chunk]
        bf16x8 kf[4][2];
        #pragma unroll
        for (int ni = 0; ni < 4; ni++) {
            kf[ni][0] = *(const bf16x8*)&kb[(ni * 16 + l15) * 48 + quad * 8];
            bf16x8 z = {};
            if (quad < 2)
                z = *(const bf16x8*)&kb[(ni * 16 + l15) * 48 + 32 + quad * 8];
            kf[ni][1] = z;   // d in [48,64) zero-masked
        }

        // S = Q K^T   (64x64, K=48 padded to 64 with zeros)
        f32x4 sacc[4][4] = {};
        #pragma unroll
        for (int mi = 0; mi < 4; mi++) {
            bf16x8 qf0 = *(const bf16x8*)&qb[(mi * 16 + l15) * 48 + quad * 8];
            bf16x8 qf1 = {};
            if (quad < 2)
                qf1 = *(const bf16x8*)&qb[(mi * 16 + l15) * 48 + 32 + quad * 8];
            #pragma unroll
            for (int ni = 0; ni < 4; ni++) {
                sacc[mi][ni] = __builtin_amdgcn_mfma_f32_16x16x32_bf16(qf0, kf[ni][0], sacc[mi][ni], 0, 0, 0);
                sacc[mi][ni] = __builtin_amdgcn_mfma_f32_16x16x32_bf16(qf1, kf[ni][1], sacc[mi][ni], 0, 0, 0);
            }
        }

        // softmax over rows (C-layout: row=quad*4+reg, col=ni*16+l15), P -> LDS
        #pragma unroll
        for (int mi = 0; mi < 4; mi++) {
            #pragma unroll
            for (int reg = 0; reg < 4; reg++) {
                float s0 = sacc[mi][0][reg] * scale;
                float s1 = sacc[mi][1][reg] * scale;
                float s2 = sacc[mi][2][reg] * scale;
                float s3 = sacc[mi][3][reg] * scale;
                float mx = fmaxf(fmaxf(s0, s1), fmaxf(s2, s3));
                #pragma unroll
                for (int off = 1; off < 16; off <<= 1)
                    mx = fmaxf(mx, __shfl_xor(mx, off));
                float e0 = __expf(s0 - mx);
                float e1 = __expf(s1 - mx);
                float e2 = __expf(s2 - mx);
                float e3 = __expf(s3 - mx);
                float sm = e0 + e1 + e2 + e3;
                #pragma unroll
                for (int off = 1; off < 16; off <<= 1)
                    sm += __shfl_xor(sm, off);
                float inv = 1.0f / sm;
                int row = mi * 16 + quad * 4 + reg;
                P[row * 72 +  0 + l15] = f2bf(e0 * inv);
                P[row * 72 + 16 + l15] = f2bf(e1 * inv);
                P[row * 72 + 32 + l15] = f2bf(e2 * inv);
                P[row * 72 + 48 + l15] = f2bf(e3 * inv);
            }
        }

        // O = P V   (64x48, K=64); V^T fragments from LDS
        bf16x8 vf[3][2];
        #pragma unroll
        for (int ni = 0; ni < 3; ni++)
            #pragma unroll
            for (int kt = 0; kt < 2; kt++)
                vf[ni][kt] = *(const bf16x8*)&VT[(ni * 16 + l15) * 72 + kt * 32 + quad * 8];

        #pragma unroll
        for (int mi = 0; mi < 4; mi++) {
            bf16x8 pf0 = *(const bf16x8*)&P[(mi * 16 + l15) * 72 + quad * 8];
            bf16x8 pf1 = *(const bf16x8*)&P[(mi * 16 + l15) * 72 + 32 + quad * 8];
            f32x4 o[3] = {};
            #pragma unroll
            for (int ni = 0; ni < 3; ni++) {
                o[ni] = __builtin_amdgcn_mfma_f32_16x16x32_bf16(pf0, vf[ni][0], o[ni], 0, 0, 0);
                o[ni] = __builtin_amdgcn_mfma_f32_16x16x32_bf16(pf1, vf[ni][1], o[ni], 0, 0, 0);
            }
            #pragma unroll
            for (int ni = 0; ni < 3; ni++)
                #pragma unroll
                for (int reg = 0; reg < 4; reg++) {
                    int tok = tok0 + mi * 16 + quad * 4 + reg;
                    attn[(size_t)tok * DIM + h * HD + ni * 16 + l15] = f2bf(o[ni][reg]);
                }
        }
    }
}

// ---------------- LayerNorm2 over y (f32) -> ln2 (bf16), row-order agnostic --
__global__ __launch_bounds__(64) void k_ln2(const float* __restrict__ y,
                                            const float* __restrict__ g,
                                            const float* __restrict__ bt,
                                            unsigned short* __restrict__ out) {
    int tok = blockIdx.x;
    int t   = threadIdx.x;
    const float* row = y + (size_t)tok * DIM;
    float v[6];
    float sum = 0.f, sq = 0.f;
    #pragma unroll
    for (int i = 0; i < 6; i++) {
        v[i] = row[i * 64 + t];
        sum += v[i]; sq += v[i] * v[i];
    }
    #pragma unroll
    for (int o = 32; o > 0; o >>= 1) {
        sum += __shfl_xor(sum, o, 64);
        sq  += __shfl_xor(sq, o, 64);
    }
    float mean = sum * (1.0f / DIM);
    float var  = sq * (1.0f / DIM) - mean * mean;
    float rstd = rsqrtf(var + 1e-5f);
    unsigned short* orow = out + (size_t)tok * DIM;
    #pragma unroll
    for (int i = 0; i < 6; i++) {
        int c = i * 64 + t;
        orow[c] = f2bf((v[i] - mean) * rstd * g[c] + bt[c]);
    }
}

extern "C" void kernel_launch(void* const* d_in, const int* in_sizes, int n_in,
                              void* d_out, int out_size, void* d_ws, size_t ws_size,
                              hipStream_t stream) {
    const float* x      = (const float*)d_in[0];
    const float* qkv_w  = (const float*)d_in[1];
    const float* qkv_b  = (const float*)d_in[2];
    const float* proj_w = (const float*)d_in[3];
    const float* proj_b = (const float*)d_in[4];
    const float* ln1_g  = (const float*)d_in[5];
    const float* ln1_b  = (const float*)d_in[6];
    const float* ln2_g  = (const float*)d_in[7];
    const float* ln2_b  = (const float*)d_in[8];
    const float* w1     = (const float*)d_in[9];
    const float* b1     = (const float*)d_in[10];
    const float* w2     = (const float*)d_in[11];
    const float* b2     = (const float*)d_in[12];

    char* ws = (char*)d_ws;
    unsigned short* qkv_wt  = (unsigned short*)(ws + 0);
    unsigned short* proj_wt = (unsigned short*)(ws + 884736);
    unsigned short* w1t     = (unsigned short*)(ws + 1179648);
    unsigned short* w2t     = (unsigned short*)(ws + 2359296);
    unsigned short* ln1     = (unsigned short*)(ws + 4194304);
    unsigned short* qkv     = (unsigned short*)(ws + 29360128);   // [3][8][32768][48]
    unsigned short* attn    = (unsigned short*)(ws + 104857600);
    float*          y       = (float*)(ws + 130023424);  // rows = pixel-raster
    unsigned short* ln2     = ln1;
    unsigned short* mid     = qkv;      // [32768][1536] bf16, rows = pixel-raster

    k_wt4<<<432, 256, 0, stream>>>(qkv_w, proj_w, w1, w2, qkv_wt, proj_wt, w1t, w2t);
    k_ln1<<<512, 256, 0, stream>>>(x, ln1_g, ln1_b, ln1);
    k_gemm_mfma<4, 384><<<9 * 256, 256, 0, stream>>>(ln1, qkv_wt, qkv_b, qkv, nullptr, 1152, 9);
    k_attn_mfma<<<NWIN, 256, 0, stream>>>(qkv, attn);
    k_gemm_mfma<2, 384><<<3 * 256, 256, 0, stream>>>(attn, proj_wt, proj_b, y, x, 384, 3);
    k_ln2<<<NTOK, 64, 0, stream>>>(y, ln2_g, ln2_b, ln2);
    k_gemm_mfma<1, 384><<<12 * 256, 256, 0, stream>>>(ln2, w1t, b1, mid, nullptr, 1536, 12);
    k_gemm_mfma<5, 1536><<<3 * 256, 256, 0, stream>>>(mid, w2t, b2, (float*)d_out, nullptr, 384, 3);
}